// Round 1
// baseline (755.308 us; speedup 1.0000x reference)
//
#include <hip/hip_runtime.h>

#define NB 16
#define NN 2048
#define DH 64
#define NSEL 228   // int(30 * ln(2048))

// ---------------------------------------------------------------------------
// Kernel A: M[b][i] = max_j (q_i . k_j) - (1/NN) * sum_j (q_i . k_j)
// fp32 register-tiled: block = 64 queries x all keys (tiles of 64).
// LDS tiles stored transposed [d][row] so inner loop is 2x ds_read_b128
// feeding 16 v_fma_f32.
// ---------------------------------------------------------------------------
__global__ __launch_bounds__(256) void rowstat_kernel(const float* __restrict__ Q,
                                                      const float* __restrict__ K,
                                                      float* __restrict__ Mout) {
  __shared__ float Qt[64][64];  // [d][q]
  __shared__ float Kt[64][64];  // [d][k]
  const int b = blockIdx.y;
  const int qbase = blockIdx.x * 64;
  const int tid = threadIdx.x;
  const int jr = tid & 63;            // row within tile
  const int dblk = (tid >> 6) * 16;   // 16-dim chunk
  const float* Qb = Q + ((size_t)b * NN + qbase) * DH;
  const float* Kb = K + (size_t)b * NN * DH;

  // load Q tile (transposed into LDS), once
  {
    const float4* src = reinterpret_cast<const float4*>(Qb + jr * DH + dblk);
    #pragma unroll
    for (int f = 0; f < 4; ++f) {
      float4 v = src[f];
      Qt[dblk + f*4 + 0][jr] = v.x;
      Qt[dblk + f*4 + 1][jr] = v.y;
      Qt[dblk + f*4 + 2][jr] = v.z;
      Qt[dblk + f*4 + 3][jr] = v.w;
    }
  }

  const int ty = tid >> 4;  // 0..15 -> query group of 4
  const int tx = tid & 15;  // 0..15 -> key group of 4
  float rmax[4], rsum[4];
  #pragma unroll
  for (int a = 0; a < 4; ++a) { rmax[a] = -3.0e38f; rsum[a] = 0.f; }

  for (int kt = 0; kt < NN / 64; ++kt) {
    __syncthreads();  // protect Kt readers of previous tile (and Qt writes, iter 0)
    {
      const float4* src =
          reinterpret_cast<const float4*>(Kb + ((size_t)(kt * 64 + jr)) * DH + dblk);
      #pragma unroll
      for (int f = 0; f < 4; ++f) {
        float4 v = src[f];
        Kt[dblk + f*4 + 0][jr] = v.x;
        Kt[dblk + f*4 + 1][jr] = v.y;
        Kt[dblk + f*4 + 2][jr] = v.z;
        Kt[dblk + f*4 + 3][jr] = v.w;
      }
    }
    __syncthreads();

    float acc[4][4];
    #pragma unroll
    for (int a = 0; a < 4; ++a)
      #pragma unroll
      for (int c = 0; c < 4; ++c) acc[a][c] = 0.f;

    #pragma unroll 8
    for (int d = 0; d < 64; ++d) {
      float qv[4], kv[4];
      *reinterpret_cast<float4*>(qv) = *reinterpret_cast<const float4*>(&Qt[d][ty * 4]);
      *reinterpret_cast<float4*>(kv) = *reinterpret_cast<const float4*>(&Kt[d][tx * 4]);
      #pragma unroll
      for (int a = 0; a < 4; ++a)
        #pragma unroll
        for (int c = 0; c < 4; ++c) acc[a][c] = fmaf(qv[a], kv[c], acc[a][c]);
    }

    #pragma unroll
    for (int a = 0; a < 4; ++a)
      #pragma unroll
      for (int c = 0; c < 4; ++c) {
        rmax[a] = fmaxf(rmax[a], acc[a][c]);
        rsum[a] += acc[a][c];
      }
  }

  // reduce across the 16 tx lanes sharing the same 4 queries (contiguous in wave)
  #pragma unroll
  for (int off = 1; off < 16; off <<= 1) {
    #pragma unroll
    for (int a = 0; a < 4; ++a) {
      rmax[a] = fmaxf(rmax[a], __shfl_xor(rmax[a], off));
      rsum[a] += __shfl_xor(rsum[a], off);
    }
  }
  if (tx == 0) {
    #pragma unroll
    for (int a = 0; a < 4; ++a)
      Mout[(size_t)b * NN + qbase + ty * 4 + a] = rmax[a] - rsum[a] * (1.0f / NN);
  }
}

// ---------------------------------------------------------------------------
// Kernel B: per-batch top-228 selection. Radix bit-search on order-preserving
// uint keys for the 228th-largest value, then scan-based compaction
// (ties resolved index-ascending, matching lax.top_k set semantics).
// ---------------------------------------------------------------------------
__global__ __launch_bounds__(256) void select_kernel(const float* __restrict__ Mvals,
                                                     int* __restrict__ Isel) {
  __shared__ unsigned int keys[NN];
  __shared__ int sa[NN];
  __shared__ int sb[NN];
  __shared__ int red[256];
  const int b = blockIdx.x;
  const int tid = threadIdx.x;

  for (int i = tid; i < NN; i += 256) {
    unsigned int uu = __float_as_uint(Mvals[(size_t)b * NN + i]);
    keys[i] = (uu & 0x80000000u) ? ~uu : (uu | 0x80000000u);
  }
  __syncthreads();

  // largest v with count(keys >= v) >= NSEL  ==  key of the NSEL-th largest
  unsigned int v = 0u;
  for (int bit = 31; bit >= 0; --bit) {
    unsigned int cand = v | (1u << bit);
    int c = 0;
    for (int i = tid; i < NN; i += 256) c += (keys[i] >= cand) ? 1 : 0;
    red[tid] = c;
    __syncthreads();
    for (int s = 128; s > 0; s >>= 1) {
      if (tid < s) red[tid] += red[tid + s];
      __syncthreads();
    }
    if (red[0] >= NSEL) v = cand;
    __syncthreads();
  }

  // pass 1: strictly-greater elements, positions via inclusive scan
  for (int i = tid; i < NN; i += 256) sa[i] = (keys[i] > v) ? 1 : 0;
  __syncthreads();
  int* src = sa;
  int* dst = sb;
  for (int off = 1; off < NN; off <<= 1) {
    for (int i = tid; i < NN; i += 256) {
      int x = src[i];
      if (i >= off) x += src[i - off];
      dst[i] = x;
    }
    __syncthreads();
    int* t = src; src = dst; dst = t;
  }
  const int cg = src[NN - 1];
  for (int i = tid; i < NN; i += 256)
    if (keys[i] > v) Isel[b * NSEL + src[i] - 1] = i;
  __syncthreads();

  // pass 2: elements == v, take lowest (NSEL - cg) indices
  const int need = NSEL - cg;
  for (int i = tid; i < NN; i += 256) sa[i] = (keys[i] == v) ? 1 : 0;
  __syncthreads();
  src = sa; dst = sb;
  for (int off = 1; off < NN; off <<= 1) {
    for (int i = tid; i < NN; i += 256) {
      int x = src[i];
      if (i >= off) x += src[i - off];
      dst[i] = x;
    }
    __syncthreads();
    int* t = src; src = dst; dst = t;
  }
  for (int i = tid; i < NN; i += 256)
    if (keys[i] == v && src[i] <= need) Isel[b * NSEL + cg + src[i] - 1] = i;
}

// ---------------------------------------------------------------------------
// Kernel C: fill out[b][i][:] = mean_d V[b][i][:]   (the literal-source quirk)
// ---------------------------------------------------------------------------
__global__ __launch_bounds__(256) void fill_kernel(const float* __restrict__ V,
                                                   float* __restrict__ out) {
  const size_t row = (size_t)blockIdx.x * 4 + (threadIdx.x >> 6);
  const int lane = threadIdx.x & 63;
  float x = V[row * DH + lane];
  #pragma unroll
  for (int off = 1; off < 64; off <<= 1) x += __shfl_xor(x, off);
  out[row * DH + lane] = x * (1.0f / DH);
}

// ---------------------------------------------------------------------------
// Kernel D: online-softmax attention for the selected rows.
// Block = 32 queries x 8 D-slice lanes; K/V tiled through LDS (32 keys/tile).
// ---------------------------------------------------------------------------
__global__ __launch_bounds__(256) void attn_kernel(const float* __restrict__ Q,
                                                   const float* __restrict__ K,
                                                   const float* __restrict__ V,
                                                   const int* __restrict__ Isel,
                                                   float* __restrict__ out) {
  __shared__ float Ks[32][64];
  __shared__ float Vs[32][64];
  const int b = blockIdx.y;
  const int g = blockIdx.x;  // query group
  const int tid = threadIdx.x;
  const int qi = tid >> 3;   // 0..31
  const int s8 = tid & 7;    // D-slice lane
  const int lq = g * 32 + qi;
  const bool active = lq < NSEL;
  const int qidx = active ? Isel[b * NSEL + lq] : 0;

  float qv[8];
  {
    const float4* qp =
        reinterpret_cast<const float4*>(Q + ((size_t)b * NN + qidx) * DH + s8 * 8);
    *reinterpret_cast<float4*>(qv) = qp[0];
    *reinterpret_cast<float4*>(qv + 4) = qp[1];
  }

  float m = -3.0e38f, l = 0.f;
  float o[8];
  #pragma unroll
  for (int d2 = 0; d2 < 8; ++d2) o[d2] = 0.f;

  for (int kt = 0; kt < NN / 32; ++kt) {
    __syncthreads();
    {
      const int r = tid >> 3;
      const int c = (tid & 7) * 8;
      const float4* ksrc =
          reinterpret_cast<const float4*>(K + ((size_t)b * NN + kt * 32 + r) * DH + c);
      const float4* vsrc =
          reinterpret_cast<const float4*>(V + ((size_t)b * NN + kt * 32 + r) * DH + c);
      *reinterpret_cast<float4*>(&Ks[r][c]) = ksrc[0];
      *reinterpret_cast<float4*>(&Ks[r][c + 4]) = ksrc[1];
      *reinterpret_cast<float4*>(&Vs[r][c]) = vsrc[0];
      *reinterpret_cast<float4*>(&Vs[r][c + 4]) = vsrc[1];
    }
    __syncthreads();

    #pragma unroll 4
    for (int j = 0; j < 32; ++j) {
      float kv[8], vv[8];
      *reinterpret_cast<float4*>(kv) = *reinterpret_cast<const float4*>(&Ks[j][s8 * 8]);
      *reinterpret_cast<float4*>(kv + 4) =
          *reinterpret_cast<const float4*>(&Ks[j][s8 * 8 + 4]);
      *reinterpret_cast<float4*>(vv) = *reinterpret_cast<const float4*>(&Vs[j][s8 * 8]);
      *reinterpret_cast<float4*>(vv + 4) =
          *reinterpret_cast<const float4*>(&Vs[j][s8 * 8 + 4]);
      float p = 0.f;
      #pragma unroll
      for (int d2 = 0; d2 < 8; ++d2) p = fmaf(qv[d2], kv[d2], p);
      p += __shfl_xor(p, 1);
      p += __shfl_xor(p, 2);
      p += __shfl_xor(p, 4);
      const float sc = p * 0.125f;  // 1/sqrt(64)
      const float mn = fmaxf(m, sc);
      const float scale = __expf(m - mn);
      const float w = __expf(sc - mn);
      l = l * scale + w;
      #pragma unroll
      for (int d2 = 0; d2 < 8; ++d2) o[d2] = fmaf(o[d2], scale, w * vv[d2]);
      m = mn;
    }
  }

  if (active) {
    const float inv = 1.0f / l;
    float4 r0, r1;
    r0.x = o[0] * inv; r0.y = o[1] * inv; r0.z = o[2] * inv; r0.w = o[3] * inv;
    r1.x = o[4] * inv; r1.y = o[5] * inv; r1.z = o[6] * inv; r1.w = o[7] * inv;
    float4* op = reinterpret_cast<float4*>(out + ((size_t)b * NN + qidx) * DH + s8 * 8);
    op[0] = r0;
    op[1] = r1;
  }
}

// ---------------------------------------------------------------------------
extern "C" void kernel_launch(void* const* d_in, const int* in_sizes, int n_in,
                              void* d_out, int out_size, void* d_ws, size_t ws_size,
                              hipStream_t stream) {
  const float* Q = (const float*)d_in[0];
  const float* K = (const float*)d_in[1];
  const float* V = (const float*)d_in[2];
  // d_in[3] (seed) intentionally unused: U == n makes the key-sampling a full
  // permutation, and max/mean over axis 1 are permutation-invariant.
  float* out = (float*)d_out;

  float* Mbuf = (float*)d_ws;                                   // NB*NN floats
  int* Isel = (int*)((char*)d_ws + (size_t)NB * NN * sizeof(float));  // NB*NSEL ints

  rowstat_kernel<<<dim3(NN / 64, NB), 256, 0, stream>>>(Q, K, Mbuf);
  select_kernel<<<dim3(NB), 256, 0, stream>>>(Mbuf, Isel);
  fill_kernel<<<dim3(NB * NN / 4), 256, 0, stream>>>(V, out);
  attn_kernel<<<dim3(8, NB), 256, 0, stream>>>(Q, K, V, Isel, out);
}

// Round 2
// 316.010 us; speedup vs baseline: 2.3901x; 2.3901x over previous
//
#include <hip/hip_runtime.h>

#define NB 16
#define NN 2048
#define DH 64
#define NSEL 228     // int(30 * ln(2048))
#define KS 8         // attention key-split chunks
#define CHUNK (NN / KS)
#define RS 2         // rowstat key-split

// ---------------------------------------------------------------------------
// Kernel A: partial row stats of S = Q K^T over a key chunk.
// Mmax/Msum laid out [RS][NB][NN]. fp32 register-tiled 4x4, transposed LDS.
// ---------------------------------------------------------------------------
__global__ __launch_bounds__(256) void rowstat_kernel(const float* __restrict__ Q,
                                                      const float* __restrict__ K,
                                                      float* __restrict__ Mmax,
                                                      float* __restrict__ Msum) {
  __shared__ float Qt[64][64];  // [d][q]
  __shared__ float Kt[64][64];  // [d][k]
  const int b = blockIdx.y;
  const int cz = blockIdx.z;
  const int qbase = blockIdx.x * 64;
  const int tid = threadIdx.x;
  const int jr = tid & 63;
  const int dblk = (tid >> 6) * 16;
  const float* Qb = Q + ((size_t)b * NN + qbase) * DH;
  const float* Kb = K + ((size_t)b * NN + cz * (NN / RS)) * DH;

  {
    const float4* src = reinterpret_cast<const float4*>(Qb + jr * DH + dblk);
    #pragma unroll
    for (int f = 0; f < 4; ++f) {
      float4 v = src[f];
      Qt[dblk + f*4 + 0][jr] = v.x;
      Qt[dblk + f*4 + 1][jr] = v.y;
      Qt[dblk + f*4 + 2][jr] = v.z;
      Qt[dblk + f*4 + 3][jr] = v.w;
    }
  }

  const int ty = tid >> 4;
  const int tx = tid & 15;
  float rmax[4], rsum[4];
  #pragma unroll
  for (int a = 0; a < 4; ++a) { rmax[a] = -3.0e38f; rsum[a] = 0.f; }

  for (int kt = 0; kt < NN / RS / 64; ++kt) {
    __syncthreads();
    {
      const float4* src =
          reinterpret_cast<const float4*>(Kb + ((size_t)(kt * 64 + jr)) * DH + dblk);
      #pragma unroll
      for (int f = 0; f < 4; ++f) {
        float4 v = src[f];
        Kt[dblk + f*4 + 0][jr] = v.x;
        Kt[dblk + f*4 + 1][jr] = v.y;
        Kt[dblk + f*4 + 2][jr] = v.z;
        Kt[dblk + f*4 + 3][jr] = v.w;
      }
    }
    __syncthreads();

    float acc[4][4];
    #pragma unroll
    for (int a = 0; a < 4; ++a)
      #pragma unroll
      for (int c = 0; c < 4; ++c) acc[a][c] = 0.f;

    #pragma unroll 8
    for (int d = 0; d < 64; ++d) {
      float qv[4], kv[4];
      *reinterpret_cast<float4*>(qv) = *reinterpret_cast<const float4*>(&Qt[d][ty * 4]);
      *reinterpret_cast<float4*>(kv) = *reinterpret_cast<const float4*>(&Kt[d][tx * 4]);
      #pragma unroll
      for (int a = 0; a < 4; ++a)
        #pragma unroll
        for (int c = 0; c < 4; ++c) acc[a][c] = fmaf(qv[a], kv[c], acc[a][c]);
    }

    #pragma unroll
    for (int a = 0; a < 4; ++a)
      #pragma unroll
      for (int c = 0; c < 4; ++c) {
        rmax[a] = fmaxf(rmax[a], acc[a][c]);
        rsum[a] += acc[a][c];
      }
  }

  #pragma unroll
  for (int off = 1; off < 16; off <<= 1) {
    #pragma unroll
    for (int a = 0; a < 4; ++a) {
      rmax[a] = fmaxf(rmax[a], __shfl_xor(rmax[a], off));
      rsum[a] += __shfl_xor(rsum[a], off);
    }
  }
  if (tx == 0) {
    #pragma unroll
    for (int a = 0; a < 4; ++a) {
      const size_t idx = ((size_t)cz * NB + b) * NN + qbase + ty * 4 + a;
      Mmax[idx] = rmax[a];
      Msum[idx] = rsum[a];
    }
  }
}

// ---------------------------------------------------------------------------
// Kernel B: per-batch top-228 (set semantics, ties index-ascending).
// Radix bit-search with wave-shfl reductions; chunked wave-scan compaction.
// ---------------------------------------------------------------------------
__global__ __launch_bounds__(256) void select_kernel(const float* __restrict__ Mmax,
                                                     const float* __restrict__ Msum,
                                                     int* __restrict__ Isel) {
  __shared__ unsigned int keys[NN];
  __shared__ int red[4];
  const int b = blockIdx.x;
  const int tid = threadIdx.x;
  const int lane = tid & 63;
  const int wid = tid >> 6;

  for (int i = tid; i < NN; i += 256) {
    const size_t i0 = (size_t)b * NN + i;
    const size_t i1 = (size_t)(NB + b) * NN + i;
    const float mv = fmaxf(Mmax[i0], Mmax[i1]);
    const float sv = Msum[i0] + Msum[i1];
    const float M = mv - sv * (1.0f / NN);
    const unsigned int uu = __float_as_uint(M);
    keys[i] = (uu & 0x80000000u) ? ~uu : (uu | 0x80000000u);
  }
  __syncthreads();

  const int base = tid * 8;  // contiguous 8-element chunk per thread
  unsigned int v = 0u;
  for (int bit = 31; bit >= 0; --bit) {
    const unsigned int cand = v | (1u << bit);
    int c = 0;
    #pragma unroll
    for (int f = 0; f < 8; ++f) c += (keys[base + f] >= cand) ? 1 : 0;
    #pragma unroll
    for (int off = 1; off < 64; off <<= 1) c += __shfl_xor(c, off);
    if (lane == 0) red[wid] = c;
    __syncthreads();
    const int total = red[0] + red[1] + red[2] + red[3];
    if (total >= NSEL) v = cand;
    __syncthreads();
  }

  // pass 1: strictly greater than v
  int flg[8];
  int cnt = 0;
  #pragma unroll
  for (int f = 0; f < 8; ++f) { flg[f] = (keys[base + f] > v) ? 1 : 0; cnt += flg[f]; }
  int scan = cnt;
  #pragma unroll
  for (int off = 1; off < 64; off <<= 1) {
    const int n = __shfl_up(scan, off);
    if (lane >= off) scan += n;
  }
  if (lane == 63) red[wid] = scan;
  __syncthreads();
  int wbase = 0;
  for (int w = 0; w < wid; ++w) wbase += red[w];
  const int cg = red[0] + red[1] + red[2] + red[3];
  int pos = wbase + scan - cnt;
  #pragma unroll
  for (int f = 0; f < 8; ++f)
    if (flg[f]) { Isel[b * NSEL + pos] = base + f; ++pos; }
  __syncthreads();

  // pass 2: equal to v, lowest (NSEL - cg) indices
  const int need = NSEL - cg;
  cnt = 0;
  #pragma unroll
  for (int f = 0; f < 8; ++f) { flg[f] = (keys[base + f] == v) ? 1 : 0; cnt += flg[f]; }
  scan = cnt;
  #pragma unroll
  for (int off = 1; off < 64; off <<= 1) {
    const int n = __shfl_up(scan, off);
    if (lane >= off) scan += n;
  }
  if (lane == 63) red[wid] = scan;
  __syncthreads();
  wbase = 0;
  for (int w = 0; w < wid; ++w) wbase += red[w];
  pos = wbase + scan - cnt;
  #pragma unroll
  for (int f = 0; f < 8; ++f)
    if (flg[f]) {
      if (pos < need) Isel[b * NSEL + cg + pos] = base + f;
      ++pos;
    }
}

// ---------------------------------------------------------------------------
// Kernel C: fill out[b][i][:] = mean_d V[b][i][:]
// ---------------------------------------------------------------------------
__global__ __launch_bounds__(256) void fill_kernel(const float* __restrict__ V,
                                                   float* __restrict__ out) {
  const size_t row = (size_t)blockIdx.x * 4 + (threadIdx.x >> 6);
  const int lane = threadIdx.x & 63;
  float x = V[row * DH + lane];
  #pragma unroll
  for (int off = 1; off < 64; off <<= 1) x += __shfl_xor(x, off);
  out[row * DH + lane] = x * (1.0f / DH);
}

// ---------------------------------------------------------------------------
// Kernel D: flash-decoding attention partials over one key chunk.
// Block = 32 queries x 8 D-lanes; per-tile (32 keys) max + single rescale.
// ---------------------------------------------------------------------------
__global__ __launch_bounds__(256) void attn_part_kernel(const float* __restrict__ Q,
                                                        const float* __restrict__ K,
                                                        const float* __restrict__ V,
                                                        const int* __restrict__ Isel,
                                                        float* __restrict__ Pm,
                                                        float* __restrict__ Pl,
                                                        float* __restrict__ Po) {
  __shared__ float Ks_[32][64];
  __shared__ float Vs_[32][64];
  const int b = blockIdx.z;
  const int kc = blockIdx.y;
  const int g = blockIdx.x;
  const int tid = threadIdx.x;
  const int qi = tid >> 3;
  const int s8 = tid & 7;
  const int lq = g * 32 + qi;
  const bool active = lq < NSEL;
  const int qidx = active ? Isel[b * NSEL + lq] : 0;

  float qv[8];
  {
    const float4* qp =
        reinterpret_cast<const float4*>(Q + ((size_t)b * NN + qidx) * DH + s8 * 8);
    *reinterpret_cast<float4*>(qv) = qp[0];
    *reinterpret_cast<float4*>(qv + 4) = qp[1];
  }

  const float* Kb = K + ((size_t)b * NN + kc * CHUNK) * DH;
  const float* Vb = V + ((size_t)b * NN + kc * CHUNK) * DH;

  float m = -3.0e38f, l = 0.f;
  float o[8];
  #pragma unroll
  for (int d2 = 0; d2 < 8; ++d2) o[d2] = 0.f;

  for (int kt = 0; kt < CHUNK / 32; ++kt) {
    __syncthreads();
    {
      const int r = tid >> 3;
      const int c = (tid & 7) * 8;
      const float4* ksrc =
          reinterpret_cast<const float4*>(Kb + ((size_t)(kt * 32 + r)) * DH + c);
      const float4* vsrc =
          reinterpret_cast<const float4*>(Vb + ((size_t)(kt * 32 + r)) * DH + c);
      *reinterpret_cast<float4*>(&Ks_[r][c]) = ksrc[0];
      *reinterpret_cast<float4*>(&Ks_[r][c + 4]) = ksrc[1];
      *reinterpret_cast<float4*>(&Vs_[r][c]) = vsrc[0];
      *reinterpret_cast<float4*>(&Vs_[r][c + 4]) = vsrc[1];
    }
    __syncthreads();

    // phase 1: all 32 scores for this tile
    float s[32];
    #pragma unroll 8
    for (int j = 0; j < 32; ++j) {
      float kv[8];
      *reinterpret_cast<float4*>(kv) = *reinterpret_cast<const float4*>(&Ks_[j][s8 * 8]);
      *reinterpret_cast<float4*>(kv + 4) =
          *reinterpret_cast<const float4*>(&Ks_[j][s8 * 8 + 4]);
      float p = 0.f;
      #pragma unroll
      for (int d2 = 0; d2 < 8; ++d2) p = fmaf(qv[d2], kv[d2], p);
      p += __shfl_xor(p, 1);
      p += __shfl_xor(p, 2);
      p += __shfl_xor(p, 4);
      s[j] = p * 0.125f;  // 1/sqrt(64)
    }

    // phase 2: tile max, single rescale
    float tm = s[0];
    #pragma unroll
    for (int j = 1; j < 32; ++j) tm = fmaxf(tm, s[j]);
    const float mn = fmaxf(m, tm);
    const float scale = __expf(m - mn);
    l *= scale;
    #pragma unroll
    for (int d2 = 0; d2 < 8; ++d2) o[d2] *= scale;
    m = mn;

    // phase 3: accumulate
    #pragma unroll 8
    for (int j = 0; j < 32; ++j) {
      const float w = __expf(s[j] - m);
      l += w;
      float vv[8];
      *reinterpret_cast<float4*>(vv) = *reinterpret_cast<const float4*>(&Vs_[j][s8 * 8]);
      *reinterpret_cast<float4*>(vv + 4) =
          *reinterpret_cast<const float4*>(&Vs_[j][s8 * 8 + 4]);
      #pragma unroll
      for (int d2 = 0; d2 < 8; ++d2) o[d2] = fmaf(w, vv[d2], o[d2]);
    }
  }

  if (active) {
    const size_t row = ((size_t)b * NSEL + lq) * KS + kc;
    if (s8 == 0) { Pm[row] = m; Pl[row] = l; }
    float4* po = reinterpret_cast<float4*>(Po + row * 64 + s8 * 8);
    float4 r0, r1;
    r0.x = o[0]; r0.y = o[1]; r0.z = o[2]; r0.w = o[3];
    r1.x = o[4]; r1.y = o[5]; r1.z = o[6]; r1.w = o[7];
    po[0] = r0;
    po[1] = r1;
  }
}

// ---------------------------------------------------------------------------
// Kernel E: merge the KS partials per selected row; write final output.
// One wave per row, lane = head dim.
// ---------------------------------------------------------------------------
__global__ __launch_bounds__(256) void combine_kernel(const int* __restrict__ Isel,
                                                      const float* __restrict__ Pm,
                                                      const float* __restrict__ Pl,
                                                      const float* __restrict__ Po,
                                                      float* __restrict__ out) {
  const int r = blockIdx.x * 4 + (threadIdx.x >> 6);
  if (r >= NB * NSEL) return;
  const int lane = threadIdx.x & 63;
  const int b = r / NSEL;
  const int qidx = Isel[r];
  const size_t base = (size_t)r * KS;

  float pm[KS];
  float gm = -3.0e38f;
  #pragma unroll
  for (int c = 0; c < KS; ++c) { pm[c] = Pm[base + c]; gm = fmaxf(gm, pm[c]); }
  float L = 0.f, od = 0.f;
  #pragma unroll
  for (int c = 0; c < KS; ++c) {
    const float e = __expf(pm[c] - gm);
    L += Pl[base + c] * e;
    od += Po[(base + c) * 64 + lane] * e;
  }
  out[((size_t)b * NN + qidx) * DH + lane] = od / L;
}

// ---------------------------------------------------------------------------
extern "C" void kernel_launch(void* const* d_in, const int* in_sizes, int n_in,
                              void* d_out, int out_size, void* d_ws, size_t ws_size,
                              hipStream_t stream) {
  const float* Q = (const float*)d_in[0];
  const float* K = (const float*)d_in[1];
  const float* V = (const float*)d_in[2];
  // d_in[3] (seed) unused: U == n -> full permutation; max/mean are
  // permutation-invariant, so M equals rowmax - rowmean of the full QK^T.
  float* out = (float*)d_out;

  float* Mmax = (float*)d_ws;                        // RS*NB*NN
  float* Msum = Mmax + (size_t)RS * NB * NN;         // RS*NB*NN
  int* Isel = (int*)(Msum + (size_t)RS * NB * NN);   // NB*NSEL
  float* Pm = (float*)(Isel + NB * NSEL);            // NB*NSEL*KS
  float* Pl = Pm + (size_t)NB * NSEL * KS;           // NB*NSEL*KS
  float* Po = Pl + (size_t)NB * NSEL * KS;           // NB*NSEL*KS*64

  rowstat_kernel<<<dim3(NN / 64, NB, RS), 256, 0, stream>>>(Q, K, Mmax, Msum);
  select_kernel<<<dim3(NB), 256, 0, stream>>>(Mmax, Msum, Isel);
  fill_kernel<<<dim3(NB * NN / 4), 256, 0, stream>>>(V, out);
  attn_part_kernel<<<dim3(8, KS, NB), 256, 0, stream>>>(Q, K, V, Isel, Pm, Pl, Po);
  combine_kernel<<<dim3((NB * NSEL + 3) / 4), 256, 0, stream>>>(Isel, Pm, Pl, Po, out);
}

// Round 3
// 295.543 us; speedup vs baseline: 2.5557x; 1.0693x over previous
//
#include <hip/hip_runtime.h>

#define NB 16
#define NN 2048
#define DH 64
#define NSEL 228     // int(30 * ln(2048))
#define KS 8         // attention key-split chunks
#define CHUNK (NN / KS)
#define RS 4         // rowstat key-split

// ---------------------------------------------------------------------------
// Kernel A: partial row stats of S = Q K^T over a key chunk of 512.
// 128q x 128k block tile, 8x8 per-thread acc, d staged in halves of 32
// (LDS 32 KB -> 4 blocks/CU with ~105 VGPR -> 50% occupancy).
// Inner loop: 64 FMA per 4 ds_read_b128.
// ---------------------------------------------------------------------------
__global__ __launch_bounds__(256, 4) void rowstat_kernel(const float* __restrict__ Q,
                                                         const float* __restrict__ K,
                                                         float* __restrict__ Mmax,
                                                         float* __restrict__ Msum) {
  __shared__ float Qt[32][128];  // [d][q]
  __shared__ float Kt[32][128];  // [d][k]
  const int b = blockIdx.y;
  const int cz = blockIdx.z;
  const int qbase = blockIdx.x * 128;
  const int tid = threadIdx.x;
  const int r = tid & 127;      // staging row
  const int h16 = (tid >> 7) * 16;  // staging d-offset (0 or 16)
  const int ty = tid >> 4;      // 0..15 -> q octet
  const int tx = tid & 15;      // 0..15 -> k octet
  const float* Qb = Q + ((size_t)b * NN + qbase) * DH;
  const float* Kb = K + ((size_t)b * NN + cz * (NN / RS)) * DH;

  float rmax[8], rsum[8];
  #pragma unroll
  for (int a = 0; a < 8; ++a) { rmax[a] = -3.0e38f; rsum[a] = 0.f; }

  for (int kt = 0; kt < NN / RS / 128; ++kt) {
    float acc[8][8];
    #pragma unroll
    for (int a = 0; a < 8; ++a)
      #pragma unroll
      for (int c = 0; c < 8; ++c) acc[a][c] = 0.f;

    #pragma unroll
    for (int half = 0; half < 2; ++half) {
      const int d0 = half * 32;
      __syncthreads();
      // stage Q half-tile (transposed) : 16 floats/thread
      {
        const float* qs = Qb + r * DH + d0 + h16;
        const float* ks = Kb + ((size_t)(kt * 128 + r)) * DH + d0 + h16;
        #pragma unroll
        for (int f = 0; f < 4; ++f) {
          float4 v = *reinterpret_cast<const float4*>(qs + f * 4);
          Qt[h16 + f * 4 + 0][r] = v.x;
          Qt[h16 + f * 4 + 1][r] = v.y;
          Qt[h16 + f * 4 + 2][r] = v.z;
          Qt[h16 + f * 4 + 3][r] = v.w;
          float4 w = *reinterpret_cast<const float4*>(ks + f * 4);
          Kt[h16 + f * 4 + 0][r] = w.x;
          Kt[h16 + f * 4 + 1][r] = w.y;
          Kt[h16 + f * 4 + 2][r] = w.z;
          Kt[h16 + f * 4 + 3][r] = w.w;
        }
      }
      __syncthreads();

      #pragma unroll 2
      for (int d = 0; d < 32; ++d) {
        float qv[8], kv[8];
        *reinterpret_cast<float4*>(qv) =
            *reinterpret_cast<const float4*>(&Qt[d][ty * 8]);
        *reinterpret_cast<float4*>(qv + 4) =
            *reinterpret_cast<const float4*>(&Qt[d][ty * 8 + 4]);
        *reinterpret_cast<float4*>(kv) =
            *reinterpret_cast<const float4*>(&Kt[d][tx * 8]);
        *reinterpret_cast<float4*>(kv + 4) =
            *reinterpret_cast<const float4*>(&Kt[d][tx * 8 + 4]);
        #pragma unroll
        for (int a = 0; a < 8; ++a)
          #pragma unroll
          for (int c = 0; c < 8; ++c) acc[a][c] = fmaf(qv[a], kv[c], acc[a][c]);
      }
    }

    #pragma unroll
    for (int a = 0; a < 8; ++a)
      #pragma unroll
      for (int c = 0; c < 8; ++c) {
        rmax[a] = fmaxf(rmax[a], acc[a][c]);
        rsum[a] += acc[a][c];
      }
  }

  // reduce across the 16 tx lanes (bits 0..3 of lane id)
  #pragma unroll
  for (int off = 1; off < 16; off <<= 1) {
    #pragma unroll
    for (int a = 0; a < 8; ++a) {
      rmax[a] = fmaxf(rmax[a], __shfl_xor(rmax[a], off));
      rsum[a] += __shfl_xor(rsum[a], off);
    }
  }
  if (tx == 0) {
    #pragma unroll
    for (int a = 0; a < 8; ++a) {
      const size_t idx = ((size_t)cz * NB + b) * NN + qbase + ty * 8 + a;
      Mmax[idx] = rmax[a];
      Msum[idx] = rsum[a];
    }
  }
}

// ---------------------------------------------------------------------------
// Kernel B: per-batch top-228 (set semantics, ties index-ascending).
// Keys held in registers (8/thread); radix bit-search + wave-scan compaction.
// ---------------------------------------------------------------------------
__global__ __launch_bounds__(256) void select_kernel(const float* __restrict__ Mmax,
                                                     const float* __restrict__ Msum,
                                                     int* __restrict__ Isel) {
  __shared__ int red[4];
  const int b = blockIdx.x;
  const int tid = threadIdx.x;
  const int lane = tid & 63;
  const int wid = tid >> 6;
  const int base = tid * 8;

  unsigned int kreg[8];
  #pragma unroll
  for (int f = 0; f < 8; ++f) {
    const int i = base + f;
    float mv = -3.0e38f, sv = 0.f;
    #pragma unroll
    for (int cz = 0; cz < RS; ++cz) {
      const size_t idx = ((size_t)cz * NB + b) * NN + i;
      mv = fmaxf(mv, Mmax[idx]);
      sv += Msum[idx];
    }
    const float M = mv - sv * (1.0f / NN);
    const unsigned int uu = __float_as_uint(M);
    kreg[f] = (uu & 0x80000000u) ? ~uu : (uu | 0x80000000u);
  }

  unsigned int v = 0u;
  for (int bit = 31; bit >= 0; --bit) {
    const unsigned int cand = v | (1u << bit);
    int c = 0;
    #pragma unroll
    for (int f = 0; f < 8; ++f) c += (kreg[f] >= cand) ? 1 : 0;
    #pragma unroll
    for (int off = 1; off < 64; off <<= 1) c += __shfl_xor(c, off);
    if (lane == 0) red[wid] = c;
    __syncthreads();
    const int total = red[0] + red[1] + red[2] + red[3];
    if (total >= NSEL) v = cand;
    __syncthreads();
  }

  // pass 1: strictly greater than v
  int flg[8];
  int cnt = 0;
  #pragma unroll
  for (int f = 0; f < 8; ++f) { flg[f] = (kreg[f] > v) ? 1 : 0; cnt += flg[f]; }
  int scan = cnt;
  #pragma unroll
  for (int off = 1; off < 64; off <<= 1) {
    const int n = __shfl_up(scan, off);
    if (lane >= off) scan += n;
  }
  if (lane == 63) red[wid] = scan;
  __syncthreads();
  int wbase = 0;
  for (int w = 0; w < wid; ++w) wbase += red[w];
  const int cg = red[0] + red[1] + red[2] + red[3];
  int pos = wbase + scan - cnt;
  #pragma unroll
  for (int f = 0; f < 8; ++f)
    if (flg[f]) { Isel[b * NSEL + pos] = base + f; ++pos; }
  __syncthreads();

  // pass 2: equal to v, lowest (NSEL - cg) indices
  const int need = NSEL - cg;
  cnt = 0;
  #pragma unroll
  for (int f = 0; f < 8; ++f) { flg[f] = (kreg[f] == v) ? 1 : 0; cnt += flg[f]; }
  scan = cnt;
  #pragma unroll
  for (int off = 1; off < 64; off <<= 1) {
    const int n = __shfl_up(scan, off);
    if (lane >= off) scan += n;
  }
  if (lane == 63) red[wid] = scan;
  __syncthreads();
  wbase = 0;
  for (int w = 0; w < wid; ++w) wbase += red[w];
  pos = wbase + scan - cnt;
  #pragma unroll
  for (int f = 0; f < 8; ++f)
    if (flg[f]) {
      if (pos < need) Isel[b * NSEL + cg + pos] = base + f;
      ++pos;
    }
}

// ---------------------------------------------------------------------------
// Kernel C: fill out[b][i][:] = mean_d V[b][i][:]
// ---------------------------------------------------------------------------
__global__ __launch_bounds__(256) void fill_kernel(const float* __restrict__ V,
                                                   float* __restrict__ out) {
  const size_t row = (size_t)blockIdx.x * 4 + (threadIdx.x >> 6);
  const int lane = threadIdx.x & 63;
  float x = V[row * DH + lane];
  #pragma unroll
  for (int off = 1; off < 64; off <<= 1) x += __shfl_xor(x, off);
  out[row * DH + lane] = x * (1.0f / DH);
}

// ---------------------------------------------------------------------------
// Kernel D: flash-decoding attention partials over one key chunk.
// Block = 32 queries x 8 D-lanes; per-tile (32 keys) max + single rescale.
// ---------------------------------------------------------------------------
__global__ __launch_bounds__(256) void attn_part_kernel(const float* __restrict__ Q,
                                                        const float* __restrict__ K,
                                                        const float* __restrict__ V,
                                                        const int* __restrict__ Isel,
                                                        float* __restrict__ Pm,
                                                        float* __restrict__ Pl,
                                                        float* __restrict__ Po) {
  __shared__ float Ks_[32][64];
  __shared__ float Vs_[32][64];
  const int b = blockIdx.z;
  const int kc = blockIdx.y;
  const int g = blockIdx.x;
  const int tid = threadIdx.x;
  const int qi = tid >> 3;
  const int s8 = tid & 7;
  const int lq = g * 32 + qi;
  const bool active = lq < NSEL;
  const int qidx = active ? Isel[b * NSEL + lq] : 0;

  float qv[8];
  {
    const float4* qp =
        reinterpret_cast<const float4*>(Q + ((size_t)b * NN + qidx) * DH + s8 * 8);
    *reinterpret_cast<float4*>(qv) = qp[0];
    *reinterpret_cast<float4*>(qv + 4) = qp[1];
  }

  const float* Kb = K + ((size_t)b * NN + kc * CHUNK) * DH;
  const float* Vb = V + ((size_t)b * NN + kc * CHUNK) * DH;

  float m = -3.0e38f, l = 0.f;
  float o[8];
  #pragma unroll
  for (int d2 = 0; d2 < 8; ++d2) o[d2] = 0.f;

  for (int kt = 0; kt < CHUNK / 32; ++kt) {
    __syncthreads();
    {
      const int rr = tid >> 3;
      const int cc = (tid & 7) * 8;
      const float4* ksrc =
          reinterpret_cast<const float4*>(Kb + ((size_t)(kt * 32 + rr)) * DH + cc);
      const float4* vsrc =
          reinterpret_cast<const float4*>(Vb + ((size_t)(kt * 32 + rr)) * DH + cc);
      *reinterpret_cast<float4*>(&Ks_[rr][cc]) = ksrc[0];
      *reinterpret_cast<float4*>(&Ks_[rr][cc + 4]) = ksrc[1];
      *reinterpret_cast<float4*>(&Vs_[rr][cc]) = vsrc[0];
      *reinterpret_cast<float4*>(&Vs_[rr][cc + 4]) = vsrc[1];
    }
    __syncthreads();

    float s[32];
    #pragma unroll 8
    for (int j = 0; j < 32; ++j) {
      float kv[8];
      *reinterpret_cast<float4*>(kv) = *reinterpret_cast<const float4*>(&Ks_[j][s8 * 8]);
      *reinterpret_cast<float4*>(kv + 4) =
          *reinterpret_cast<const float4*>(&Ks_[j][s8 * 8 + 4]);
      float p = 0.f;
      #pragma unroll
      for (int d2 = 0; d2 < 8; ++d2) p = fmaf(qv[d2], kv[d2], p);
      p += __shfl_xor(p, 1);
      p += __shfl_xor(p, 2);
      p += __shfl_xor(p, 4);
      s[j] = p * 0.125f;  // 1/sqrt(64)
    }

    float tm = s[0];
    #pragma unroll
    for (int j = 1; j < 32; ++j) tm = fmaxf(tm, s[j]);
    const float mn = fmaxf(m, tm);
    const float scale = __expf(m - mn);
    l *= scale;
    #pragma unroll
    for (int d2 = 0; d2 < 8; ++d2) o[d2] *= scale;
    m = mn;

    #pragma unroll 8
    for (int j = 0; j < 32; ++j) {
      const float w = __expf(s[j] - m);
      l += w;
      float vv[8];
      *reinterpret_cast<float4*>(vv) = *reinterpret_cast<const float4*>(&Vs_[j][s8 * 8]);
      *reinterpret_cast<float4*>(vv + 4) =
          *reinterpret_cast<const float4*>(&Vs_[j][s8 * 8 + 4]);
      #pragma unroll
      for (int d2 = 0; d2 < 8; ++d2) o[d2] = fmaf(w, vv[d2], o[d2]);
    }
  }

  if (active) {
    const size_t row = ((size_t)b * NSEL + lq) * KS + kc;
    if (s8 == 0) { Pm[row] = m; Pl[row] = l; }
    float4* po = reinterpret_cast<float4*>(Po + row * 64 + s8 * 8);
    float4 r0, r1;
    r0.x = o[0]; r0.y = o[1]; r0.z = o[2]; r0.w = o[3];
    r1.x = o[4]; r1.y = o[5]; r1.z = o[6]; r1.w = o[7];
    po[0] = r0;
    po[1] = r1;
  }
}

// ---------------------------------------------------------------------------
// Kernel E: merge the KS partials per selected row; write final output.
// ---------------------------------------------------------------------------
__global__ __launch_bounds__(256) void combine_kernel(const int* __restrict__ Isel,
                                                      const float* __restrict__ Pm,
                                                      const float* __restrict__ Pl,
                                                      const float* __restrict__ Po,
                                                      float* __restrict__ out) {
  const int r = blockIdx.x * 4 + (threadIdx.x >> 6);
  if (r >= NB * NSEL) return;
  const int lane = threadIdx.x & 63;
  const int b = r / NSEL;
  const int qidx = Isel[r];
  const size_t base = (size_t)r * KS;

  float pm[KS];
  float gm = -3.0e38f;
  #pragma unroll
  for (int c = 0; c < KS; ++c) { pm[c] = Pm[base + c]; gm = fmaxf(gm, pm[c]); }
  float L = 0.f, od = 0.f;
  #pragma unroll
  for (int c = 0; c < KS; ++c) {
    const float e = __expf(pm[c] - gm);
    L += Pl[base + c] * e;
    od += Po[(base + c) * 64 + lane] * e;
  }
  out[((size_t)b * NN + qidx) * DH + lane] = od / L;
}

// ---------------------------------------------------------------------------
extern "C" void kernel_launch(void* const* d_in, const int* in_sizes, int n_in,
                              void* d_out, int out_size, void* d_ws, size_t ws_size,
                              hipStream_t stream) {
  const float* Q = (const float*)d_in[0];
  const float* K = (const float*)d_in[1];
  const float* V = (const float*)d_in[2];
  // d_in[3] (seed) unused: U == n -> full permutation; max/mean are
  // permutation-invariant, so M equals rowmax - rowmean of the full QK^T.
  float* out = (float*)d_out;

  float* Mmax = (float*)d_ws;                        // RS*NB*NN
  float* Msum = Mmax + (size_t)RS * NB * NN;         // RS*NB*NN
  int* Isel = (int*)(Msum + (size_t)RS * NB * NN);   // NB*NSEL
  float* Pm = (float*)(Isel + NB * NSEL);            // NB*NSEL*KS
  float* Pl = Pm + (size_t)NB * NSEL * KS;           // NB*NSEL*KS
  float* Po = Pl + (size_t)NB * NSEL * KS;           // NB*NSEL*KS*64

  rowstat_kernel<<<dim3(NN / 128, NB, RS), 256, 0, stream>>>(Q, K, Mmax, Msum);
  select_kernel<<<dim3(NB), 256, 0, stream>>>(Mmax, Msum, Isel);
  fill_kernel<<<dim3(NB * NN / 4), 256, 0, stream>>>(V, out);
  attn_part_kernel<<<dim3(8, KS, NB), 256, 0, stream>>>(Q, K, V, Isel, Pm, Pl, Po);
  combine_kernel<<<dim3((NB * NSEL + 3) / 4), 256, 0, stream>>>(Isel, Pm, Pl, Po, out);
}